// Round 1
// baseline (34.563 us; speedup 1.0000x reference)
//
#include <hip/hip_runtime.h>

// DiceLoss: input [N=32, C=4, H=512, W=512] f32, target [N,1,H,W] i32.
// softmax over C; loss = 1 - (2/(N*(2*HW+eps))) * sum_{all pixels} probs[target].
// (cardinality = sum(probs) + HW = 2*HW exactly since softmax sums to 1.)

constexpr int N_   = 32;
constexpr int C_   = 4;
constexpr int HW_  = 512 * 512;          // 262144 = 2^18
constexpr float EPSF = 1e-6f;

__global__ __launch_bounds__(256) void dice_partial(
        const float* __restrict__ x,
        const int*   __restrict__ tgt,
        float*       __restrict__ partial,
        int ngroups) {
    int tid    = blockIdx.x * blockDim.x + threadIdx.x;
    int stride = gridDim.x * blockDim.x;
    float acc = 0.f;

    for (int g = tid; g < ngroups; g += stride) {
        int pix = g << 2;                    // 4 pixels per group
        int n   = pix >> 18;                 // / HW_
        int hw  = pix & (HW_ - 1);
        const float* base = x + (size_t)n * C_ * HW_ + hw;

        float4 v0 = *reinterpret_cast<const float4*>(base);
        float4 v1 = *reinterpret_cast<const float4*>(base + HW_);
        float4 v2 = *reinterpret_cast<const float4*>(base + 2 * (size_t)HW_);
        float4 v3 = *reinterpret_cast<const float4*>(base + 3 * (size_t)HW_);
        int4   t4 = *reinterpret_cast<const int4*>(tgt + (size_t)n * HW_ + hw);

        const float* a0 = reinterpret_cast<const float*>(&v0);
        const float* a1 = reinterpret_cast<const float*>(&v1);
        const float* a2 = reinterpret_cast<const float*>(&v2);
        const float* a3 = reinterpret_cast<const float*>(&v3);
        const int*   tt = reinterpret_cast<const int*>(&t4);

        #pragma unroll
        for (int j = 0; j < 4; ++j) {        // j compile-time after unroll -> no scratch
            float a = a0[j], b = a1[j], c = a2[j], d = a3[j];
            int   t = tt[j];
            float m  = fmaxf(fmaxf(a, b), fmaxf(c, d));
            float ea = __expf(a - m);
            float eb = __expf(b - m);
            float ec = __expf(c - m);
            float ed = __expf(d - m);
            float denom = (ea + eb) + (ec + ed);
            float et = (t == 0) ? ea : (t == 1) ? eb : (t == 2) ? ec : ed;
            acc += et / denom;
        }
    }

    // wave (64-lane) reduce
    #pragma unroll
    for (int off = 32; off > 0; off >>= 1)
        acc += __shfl_down(acc, off, 64);

    __shared__ float wsum[4];
    int lane = threadIdx.x & 63;
    int wid  = threadIdx.x >> 6;
    if (lane == 0) wsum[wid] = acc;
    __syncthreads();
    if (threadIdx.x == 0)
        partial[blockIdx.x] = (wsum[0] + wsum[1]) + (wsum[2] + wsum[3]);
}

__global__ __launch_bounds__(256) void dice_final(
        const float* __restrict__ partial, int nblk, float* __restrict__ out) {
    float acc = 0.f;
    for (int i = threadIdx.x; i < nblk; i += blockDim.x)
        acc += partial[i];

    #pragma unroll
    for (int off = 32; off > 0; off >>= 1)
        acc += __shfl_down(acc, off, 64);

    __shared__ float wsum[4];
    int lane = threadIdx.x & 63;
    int wid  = threadIdx.x >> 6;
    if (lane == 0) wsum[wid] = acc;
    __syncthreads();
    if (threadIdx.x == 0) {
        float S    = (wsum[0] + wsum[1]) + (wsum[2] + wsum[3]);
        float card = 2.0f * (float)HW_ + EPSF;
        out[0] = 1.0f - 2.0f * S / ((float)N_ * card);
    }
}

extern "C" void kernel_launch(void* const* d_in, const int* in_sizes, int n_in,
                              void* d_out, int out_size, void* d_ws, size_t ws_size,
                              hipStream_t stream) {
    const float* x   = (const float*)d_in[0];
    const int*   tgt = (const int*)d_in[1];
    float*       out = (float*)d_out;
    float*       par = (float*)d_ws;

    int nblk = 2048;                                      // 8 blocks/CU target
    if (ws_size < (size_t)nblk * sizeof(float))
        nblk = (int)(ws_size / sizeof(float));
    if (nblk < 1) nblk = 1;

    constexpr int ngroups = N_ * HW_ / 4;                 // 2,097,152 float4-groups

    dice_partial<<<nblk, 256, 0, stream>>>(x, tgt, par, ngroups);
    dice_final<<<1, 256, 0, stream>>>(par, nblk, out);
}

// Round 2
// 34.428 us; speedup vs baseline: 1.0039x; 1.0039x over previous
//
#include <hip/hip_runtime.h>

// DiceLoss: input [N=32, C=4, H=512, W=512] f32, target [N,1,H,W] i32.
// softmax over C; loss = 1 - (2/(N*(2*HW+eps))) * sum_{all pixels} probs[target].
// (cardinality = sum(probs) + HW = 2*HW exactly since softmax sums to 1.)

constexpr int N_   = 32;
constexpr int C_   = 4;
constexpr int HW_  = 512 * 512;          // 262144 = 2^18
constexpr float EPSF = 1e-6f;

__global__ __launch_bounds__(256) void dice_partial(
        const float* __restrict__ x,
        const int*   __restrict__ tgt,
        float*       __restrict__ partial,
        int ngroups) {
    int tid    = blockIdx.x * blockDim.x + threadIdx.x;
    int stride = gridDim.x * blockDim.x;
    float acc = 0.f;

    for (int g = tid; g < ngroups; g += stride) {
        int pix = g << 2;                    // 4 pixels per group
        int n   = pix >> 18;                 // / HW_
        int hw  = pix & (HW_ - 1);
        const float* base = x + (size_t)n * C_ * HW_ + hw;

        float4 v0 = *reinterpret_cast<const float4*>(base);
        float4 v1 = *reinterpret_cast<const float4*>(base + HW_);
        float4 v2 = *reinterpret_cast<const float4*>(base + 2 * (size_t)HW_);
        float4 v3 = *reinterpret_cast<const float4*>(base + 3 * (size_t)HW_);
        int4   t4 = *reinterpret_cast<const int4*>(tgt + (size_t)n * HW_ + hw);

        const float* a0 = reinterpret_cast<const float*>(&v0);
        const float* a1 = reinterpret_cast<const float*>(&v1);
        const float* a2 = reinterpret_cast<const float*>(&v2);
        const float* a3 = reinterpret_cast<const float*>(&v3);
        const int*   tt = reinterpret_cast<const int*>(&t4);

        #pragma unroll
        for (int j = 0; j < 4; ++j) {        // j compile-time after unroll -> no scratch
            float a = a0[j], b = a1[j], c = a2[j], d = a3[j];
            int   t = tt[j];
            float m  = fmaxf(fmaxf(a, b), fmaxf(c, d));
            float ea = __expf(a - m);
            float eb = __expf(b - m);
            float ec = __expf(c - m);
            float ed = __expf(d - m);
            float denom = (ea + eb) + (ec + ed);
            float et = (t == 0) ? ea : (t == 1) ? eb : (t == 2) ? ec : ed;
            acc += et / denom;
        }
    }

    // wave (64-lane) reduce
    #pragma unroll
    for (int off = 32; off > 0; off >>= 1)
        acc += __shfl_down(acc, off, 64);

    __shared__ float wsum[4];
    int lane = threadIdx.x & 63;
    int wid  = threadIdx.x >> 6;
    if (lane == 0) wsum[wid] = acc;
    __syncthreads();
    if (threadIdx.x == 0)
        partial[blockIdx.x] = (wsum[0] + wsum[1]) + (wsum[2] + wsum[3]);
}

__global__ __launch_bounds__(256) void dice_final(
        const float* __restrict__ partial, int nblk, float* __restrict__ out) {
    float acc = 0.f;
    for (int i = threadIdx.x; i < nblk; i += blockDim.x)
        acc += partial[i];

    #pragma unroll
    for (int off = 32; off > 0; off >>= 1)
        acc += __shfl_down(acc, off, 64);

    __shared__ float wsum[4];
    int lane = threadIdx.x & 63;
    int wid  = threadIdx.x >> 6;
    if (lane == 0) wsum[wid] = acc;
    __syncthreads();
    if (threadIdx.x == 0) {
        float S    = (wsum[0] + wsum[1]) + (wsum[2] + wsum[3]);
        float card = 2.0f * (float)HW_ + EPSF;
        out[0] = 1.0f - 2.0f * S / ((float)N_ * card);
    }
}

extern "C" void kernel_launch(void* const* d_in, const int* in_sizes, int n_in,
                              void* d_out, int out_size, void* d_ws, size_t ws_size,
                              hipStream_t stream) {
    const float* x   = (const float*)d_in[0];
    const int*   tgt = (const int*)d_in[1];
    float*       out = (float*)d_out;
    float*       par = (float*)d_ws;

    int nblk = 2048;                                      // 8 blocks/CU target
    if (ws_size < (size_t)nblk * sizeof(float))
        nblk = (int)(ws_size / sizeof(float));
    if (nblk < 1) nblk = 1;

    constexpr int ngroups = N_ * HW_ / 4;                 // 2,097,152 float4-groups

    dice_partial<<<nblk, 256, 0, stream>>>(x, tgt, par, ngroups);
    dice_final<<<1, 256, 0, stream>>>(par, nblk, out);
}

// Round 3
// 33.657 us; speedup vs baseline: 1.0269x; 1.0229x over previous
//
#include <hip/hip_runtime.h>

// DiceLoss: input [N=32, C=4, H=512, W=512] f32, target [N,1,H,W] i32.
// softmax over C; loss = 1 - (2/(N*(2*HW+eps))) * sum_{all pixels} probs[target].
// (cardinality = sum(probs) + HW = 2*HW exactly since softmax sums to 1.)

constexpr int N_   = 32;
constexpr int C_   = 4;
constexpr int HW_  = 512 * 512;          // 262144 = 2^18
constexpr float EPSF = 1e-6f;

__global__ __launch_bounds__(256) void dice_partial(
        const float* __restrict__ x,
        const int*   __restrict__ tgt,
        float*       __restrict__ partial,
        int ngroups) {
    int tid    = blockIdx.x * blockDim.x + threadIdx.x;
    int stride = gridDim.x * blockDim.x;
    float acc = 0.f;

    for (int g = tid; g < ngroups; g += stride) {
        int pix = g << 2;                    // 4 pixels per group
        int n   = pix >> 18;                 // / HW_
        int hw  = pix & (HW_ - 1);
        const float* base = x + (size_t)n * C_ * HW_ + hw;

        float4 v0 = *reinterpret_cast<const float4*>(base);
        float4 v1 = *reinterpret_cast<const float4*>(base + HW_);
        float4 v2 = *reinterpret_cast<const float4*>(base + 2 * (size_t)HW_);
        float4 v3 = *reinterpret_cast<const float4*>(base + 3 * (size_t)HW_);
        int4   t4 = *reinterpret_cast<const int4*>(tgt + (size_t)n * HW_ + hw);

        const float* a0 = reinterpret_cast<const float*>(&v0);
        const float* a1 = reinterpret_cast<const float*>(&v1);
        const float* a2 = reinterpret_cast<const float*>(&v2);
        const float* a3 = reinterpret_cast<const float*>(&v3);
        const int*   tt = reinterpret_cast<const int*>(&t4);

        #pragma unroll
        for (int j = 0; j < 4; ++j) {        // j compile-time after unroll -> no scratch
            float a = a0[j], b = a1[j], c = a2[j], d = a3[j];
            int   t = tt[j];
            float m  = fmaxf(fmaxf(a, b), fmaxf(c, d));
            float ea = __expf(a - m);
            float eb = __expf(b - m);
            float ec = __expf(c - m);
            float ed = __expf(d - m);
            float denom = (ea + eb) + (ec + ed);
            float et = (t == 0) ? ea : (t == 1) ? eb : (t == 2) ? ec : ed;
            acc += et / denom;
        }
    }

    // wave (64-lane) reduce
    #pragma unroll
    for (int off = 32; off > 0; off >>= 1)
        acc += __shfl_down(acc, off, 64);

    __shared__ float wsum[4];
    int lane = threadIdx.x & 63;
    int wid  = threadIdx.x >> 6;
    if (lane == 0) wsum[wid] = acc;
    __syncthreads();
    if (threadIdx.x == 0)
        partial[blockIdx.x] = (wsum[0] + wsum[1]) + (wsum[2] + wsum[3]);
}

__global__ __launch_bounds__(256) void dice_final(
        const float* __restrict__ partial, int nblk, float* __restrict__ out) {
    float acc = 0.f;
    for (int i = threadIdx.x; i < nblk; i += blockDim.x)
        acc += partial[i];

    #pragma unroll
    for (int off = 32; off > 0; off >>= 1)
        acc += __shfl_down(acc, off, 64);

    __shared__ float wsum[4];
    int lane = threadIdx.x & 63;
    int wid  = threadIdx.x >> 6;
    if (lane == 0) wsum[wid] = acc;
    __syncthreads();
    if (threadIdx.x == 0) {
        float S    = (wsum[0] + wsum[1]) + (wsum[2] + wsum[3]);
        float card = 2.0f * (float)HW_ + EPSF;
        out[0] = 1.0f - 2.0f * S / ((float)N_ * card);
    }
}

extern "C" void kernel_launch(void* const* d_in, const int* in_sizes, int n_in,
                              void* d_out, int out_size, void* d_ws, size_t ws_size,
                              hipStream_t stream) {
    const float* x   = (const float*)d_in[0];
    const int*   tgt = (const int*)d_in[1];
    float*       out = (float*)d_out;
    float*       par = (float*)d_ws;

    int nblk = 2048;                                      // 8 blocks/CU target
    if (ws_size < (size_t)nblk * sizeof(float))
        nblk = (int)(ws_size / sizeof(float));
    if (nblk < 1) nblk = 1;

    constexpr int ngroups = N_ * HW_ / 4;                 // 2,097,152 float4-groups

    dice_partial<<<nblk, 256, 0, stream>>>(x, tgt, par, ngroups);
    dice_final<<<1, 256, 0, stream>>>(par, nblk, out);
}